// Round 20
// baseline (543.153 us; speedup 1.0000x reference)
//
#include <hip/hip_runtime.h>
#include <hip/hip_bf16.h>

#define B_SZ 16
#define CIN 256
#define EDIM 256
#define NE 8192
#define HW 32
#define NPIX (B_SZ*HW*HW)          // 16384
#define OUT_ELEMS (B_SZ*CIN*HW*HW) // 4194304
#define SCREEN_T 3.2e-4f
#define CAND_SLOTS 128

typedef __attribute__((ext_vector_type(8))) short short8;
typedef __attribute__((ext_vector_type(4))) short short4v;
typedef __attribute__((ext_vector_type(4))) float f32x4;

// ---------------- helpers ----------------
__device__ __forceinline__ float block_sum(float v, float* sbuf) {
    #pragma unroll
    for (int off = 32; off > 0; off >>= 1) v += __shfl_down(v, off, 64);
    int wid = threadIdx.x >> 6;
    int lane = threadIdx.x & 63;
    if (lane == 0) sbuf[wid] = v;
    __syncthreads();
    if (threadIdx.x == 0) sbuf[0] = sbuf[0] + sbuf[1] + sbuf[2] + sbuf[3];
    __syncthreads();
    float r = sbuf[0];
    __syncthreads();
    return r;
}

__device__ __forceinline__ double wave_sum_d(double v) {
    #pragma unroll
    for (int off = 32; off > 0; off >>= 1) v += __shfl_down(v, off, 64);
    return __shfl(v, 0, 64);
}

__device__ __forceinline__ unsigned short bf16rne(float f) {
    unsigned int u = __float_as_uint(f);
    unsigned int r = (u + 0x7FFFu + ((u >> 16) & 1u)) >> 16;
    return (unsigned short)r;
}
__device__ __forceinline__ float bf2f(unsigned short h) {
    return __uint_as_float((unsigned int)h << 16);
}

// monotone map float -> uint (order-preserving), and inverse
__device__ __forceinline__ unsigned int mapU(float f) {
    unsigned int u = __float_as_uint(f);
    return (u & 0x80000000u) ? ~u : (u | 0x80000000u);
}
__device__ __forceinline__ float unmapU(unsigned int m) {
    unsigned int u = (m & 0x80000000u) ? (m ^ 0x80000000u) : ~m;
    return __uint_as_float(u);
}

// ---------------- fused prep: w1 bf16 hi/lo + w2 bf16 hi/lo + codebook bf16 hi/lo ----------
__global__ void prep_kernel(const float* __restrict__ emb_w, unsigned short* __restrict__ w1bh,
                            unsigned short* __restrict__ w1bl,
                            const float* __restrict__ unemb_w, unsigned short* __restrict__ w2hi,
                            unsigned short* __restrict__ w2lo, const float* __restrict__ cb,
                            unsigned short* __restrict__ cbhi, unsigned short* __restrict__ cblo) {
    int blk = blockIdx.x;
    if (blk < 2304) {
        int e = blk / 9, tap = blk % 9;
        int c = threadIdx.x;
        float v = emb_w[(size_t)e * 2304 + c * 9 + tap];
        unsigned short h = bf16rne(v);
        unsigned short l = bf16rne(v - bf2f(h));
        size_t j = (size_t)e * 2304 + tap * 256 + c;
        w1bh[j] = h; w1bl[j] = l;
    } else if (blk < 4608) {
        int b2 = blk - 2304;
        int cout = b2 / 9, tap = b2 % 9;
        int e = threadIdx.x;
        float v = unemb_w[(size_t)cout * 2304 + e * 9 + tap];
        unsigned short h = bf16rne(v);
        unsigned short l = bf16rne(v - bf2f(h));
        size_t j = (size_t)cout * 2304 + tap * 256 + e;
        w2hi[j] = h; w2lo[j] = l;
    } else {
        int i = (blk - 4608) * 256 + threadIdx.x;
        size_t base = (size_t)i * 4;
        float4 v = *(const float4*)(cb + base);
        short4v sh, sl;
        unsigned short h;
        h = bf16rne(v.x); sh[0] = (short)h; sl[0] = (short)bf16rne(v.x - bf2f(h));
        h = bf16rne(v.y); sh[1] = (short)h; sl[1] = (short)bf16rne(v.y - bf2f(h));
        h = bf16rne(v.z); sh[2] = (short)h; sl[2] = (short)bf16rne(v.z - bf2f(h));
        h = bf16rne(v.w); sh[3] = (short)h; sl[3] = (short)bf16rne(v.w - bf2f(h));
        *(short4v*)(cbhi + base) = sh;
        *(short4v*)(cblo + base) = sl;
    }
}

// ---------------- emb conv as split-bf16 MFMA implicit GEMM ----------------
// Row stride 80 B (was 64): start bank = (row*20 + slot*4) mod 32, period-8 in row
// -> worst-case 2-way LDS conflict (free) instead of 4-way. Same data, pure layout change.
#define EM_ROWB 80
#define EM_REG 8160   // bytes per split region: 102 rows x 80 B
__global__ __launch_bounds__(256, 4) void conv_emb_mfma(const float* __restrict__ z,
                                                        const unsigned short* __restrict__ w1bh,
                                                        const unsigned short* __restrict__ w1bl,
                                                        float* __restrict__ ze) {
    __shared__ char smem[3 * EM_REG];   // 24480 B
    const int tid = threadIdx.x;
    const int wid = tid >> 6, lane = tid & 63;
    const int l15 = lane & 15, lg = lane >> 4;
    const int bh = blockIdx.x;
    const int b = bh >> 5, h = bh & 31;
    const int ch = blockIdx.y;

    for (int i = tid; i < (3 * EM_REG) / 16; i += 256) ((int4*)smem)[i] = make_int4(0, 0, 0, 0);

    const f32x4 zero4 = {0.f, 0.f, 0.f, 0.f};
    f32x4 acc[2][2];
    acc[0][0] = zero4; acc[0][1] = zero4; acc[1][0] = zero4; acc[1][1] = zero4;

    for (int cc = 0; cc < 256; cc += 32) {
        __syncthreads();
        #pragma unroll
        for (int rd = 0; rd < 2; ++rd) {
            int t2 = rd * 256 + tid;
            if (t2 < 408) {
                int row = t2 >> 2;              // 0..101 = r*34 + wp
                int oct = t2 & 3;               // c-octet
                int r = row / 34, wp = row - r * 34;
                int hh = h + r - 1;
                if (hh >= 0 && hh < 32 && wp >= 1 && wp <= 32) {
                    const float* zp = z + (size_t)b * 262144 + (size_t)(cc + oct * 8) * 1024
                                    + hh * 32 + (wp - 1);
                    short8 vh, vm, vl;
                    #pragma unroll
                    for (int j = 0; j < 8; ++j) {
                        float v = zp[(size_t)j * 1024];
                        unsigned short h1 = bf16rne(v);
                        float rm = v - bf2f(h1);
                        unsigned short m1 = bf16rne(rm);
                        float rl = rm - bf2f(m1);
                        unsigned short l1 = bf16rne(rl);
                        vh[j] = (short)h1; vm[j] = (short)m1; vl[j] = (short)l1;
                    }
                    int boff = row * EM_ROWB + ((oct * 16) ^ ((wp & 3) << 4));
                    *(short8*)(smem + boff) = vh;
                    *(short8*)(smem + EM_REG + boff) = vm;
                    *(short8*)(smem + 2 * EM_REG + boff) = vl;
                }
            }
        }
        __syncthreads();

        #pragma unroll
        for (int tap = 0; tap < 9; ++tap) {
            const int r = tap / 3, kw = tap % 3;
            short8 a1[2], a2[2], a3[2], bhf[2], blf[2];
            #pragma unroll
            for (int mf = 0; mf < 2; ++mf) {
                int wpr = mf * 16 + l15 + kw;   // 0..33
                int boff = (r * 34 + wpr) * EM_ROWB + ((lg * 16) ^ ((wpr & 3) << 4));
                a1[mf] = *(const short8*)(smem + boff);
                a2[mf] = *(const short8*)(smem + EM_REG + boff);
                a3[mf] = *(const short8*)(smem + 2 * EM_REG + boff);
            }
            #pragma unroll
            for (int nf = 0; nf < 2; ++nf) {
                int e_idx = (ch << 7) + (wid << 5) + (nf << 4) + l15;
                size_t goff = (size_t)e_idx * 2304 + tap * 256 + cc + lg * 8;
                bhf[nf] = *(const short8*)(w1bh + goff);
                blf[nf] = *(const short8*)(w1bl + goff);
            }
            #pragma unroll
            for (int mf = 0; mf < 2; ++mf)
                #pragma unroll
                for (int nf = 0; nf < 2; ++nf) {
                    acc[mf][nf] = __builtin_amdgcn_mfma_f32_16x16x32_bf16(a1[mf], bhf[nf], acc[mf][nf], 0, 0, 0);
                    acc[mf][nf] = __builtin_amdgcn_mfma_f32_16x16x32_bf16(a1[mf], blf[nf], acc[mf][nf], 0, 0, 0);
                    acc[mf][nf] = __builtin_amdgcn_mfma_f32_16x16x32_bf16(a2[mf], bhf[nf], acc[mf][nf], 0, 0, 0);
                    acc[mf][nf] = __builtin_amdgcn_mfma_f32_16x16x32_bf16(a2[mf], blf[nf], acc[mf][nf], 0, 0, 0);
                    acc[mf][nf] = __builtin_amdgcn_mfma_f32_16x16x32_bf16(a3[mf], bhf[nf], acc[mf][nf], 0, 0, 0);
                }
        }
    }

    int p0 = (b * 32 + h) * 32;
    #pragma unroll
    for (int mf = 0; mf < 2; ++mf)
        #pragma unroll
        for (int nf = 0; nf < 2; ++nf) {
            int e_idx = (ch << 7) + (wid << 5) + (nf << 4) + l15;
            #pragma unroll
            for (int rr = 0; rr < 4; ++rr) {
                int pix = mf * 16 + lg * 4 + rr;
                ze[(size_t)(p0 + pix) * 256 + e_idx] = acc[mf][nf][rr];
            }
        }
}

// ---------------- layernorm: wave-per-pixel, read-only ze (bias applied on the fly) --------
__global__ __launch_bounds__(256) void ln_kernel(const float* __restrict__ ze, const float* __restrict__ bias,
                                                 const float* __restrict__ g,
                                                 const float* __restrict__ bta,
                                                 unsigned short* __restrict__ zfb,
                                                 float* __restrict__ snorm, float* __restrict__ mu_a,
                                                 float* __restrict__ r_a) {
    int wid = threadIdx.x >> 6, lane = threadIdx.x & 63;
    int p = blockIdx.x * 4 + wid;
    const float* zp = ze + (size_t)p * 256;
    float x0 = zp[lane]       + bias[lane];
    float x1 = zp[lane + 64]  + bias[lane + 64];
    float x2 = zp[lane + 128] + bias[lane + 128];
    float x3 = zp[lane + 192] + bias[lane + 192];
    double lsum = (((double)x0 + (double)x1) + (double)x2) + (double)x3;
    double sum = wave_sum_d(lsum);
    float mu = ((float)sum) / 256.0f;
    float e0 = x0 - mu, e1 = x1 - mu, e2 = x2 - mu, e3 = x3 - mu;
    double lsq = (((double)(e0 * e0) + (double)(e1 * e1)) + (double)(e2 * e2)) + (double)(e3 * e3);
    double vs = wave_sum_d(lsq);
    float var = ((float)vs) / 256.0f;
    float r = 1.0f / sqrtf(var + 1e-5f);
    float y0 = ((e0 * r) * g[lane])       + bta[lane];
    float y1 = ((e1 * r) * g[lane + 64])  + bta[lane + 64];
    float y2 = ((e2 * r) * g[lane + 128]) + bta[lane + 128];
    float y3 = ((e3 * r) * g[lane + 192]) + bta[lane + 192];
    unsigned short* zq = zfb + (size_t)p * 256;
    zq[lane] = bf16rne(y0); zq[lane + 64] = bf16rne(y1);
    zq[lane + 128] = bf16rne(y2); zq[lane + 192] = bf16rne(y3);
    double lys = (((double)(y0 * y0) + (double)(y1 * y1)) + (double)(y2 * y2)) + (double)(y3 * y3);
    double ss = wave_sum_d(lys);
    if (lane == 0) { snorm[p] = (float)ss; mu_a[p] = mu; r_a[p] = r; }
}

// ---------------- single-pass screening: register-rotation pipelined B stream ----------------
__global__ __launch_bounds__(512) void screen_kernel(const unsigned short* __restrict__ zf_bf,
                                                     const unsigned short* __restrict__ cb_bf,
                                                     int* __restrict__ ccnt,
                                                     int* __restrict__ cand) {
    __shared__ unsigned int smax[64];
    __shared__ int scnt[64];
    __shared__ int sbuf[64][CAND_SLOTS];   // 32 KB
    const int tid = threadIdx.x;
    const int w = tid >> 6;
    const int lane = tid & 63;
    const int l15 = lane & 15, lg = lane >> 4;
    const int p0 = blockIdx.x * 64;
    const int rowoff = w * 16 + l15;
    const int lg8 = lg * 8;

    if (tid < 64) { smax[tid] = 0u; scnt[tid] = 0; }
    __syncthreads();

    short8 aF[4][8];
    #pragma unroll
    for (int mf = 0; mf < 4; ++mf)
        #pragma unroll
        for (int ks = 0; ks < 8; ++ks)
            aF[mf][ks] = *reinterpret_cast<const short8*>(
                zf_bf + (size_t)(p0 + mf * 16 + l15) * 256 + ks * 32 + lg8);

    const f32x4 zero4 = {0.f, 0.f, 0.f, 0.f};
    float runL[4][4], runS[4][4];
    #pragma unroll
    for (int mf = 0; mf < 4; ++mf)
        #pragma unroll
        for (int r = 0; r < 4; ++r) { runL[mf][r] = -3.4e38f; runS[mf][r] = -3.4e38f; }

    const unsigned short* basep = cb_bf + (size_t)rowoff * 256 + lg8;

    // ---- seed pass: n = 0..255 (2 chunks), max only ----
    for (int c = 0; c < 2; ++c) {
        const unsigned short* bp = basep + (size_t)c * 128 * 256;
        short8 bF[8];
        #pragma unroll
        for (int ks = 0; ks < 8; ++ks) bF[ks] = *reinterpret_cast<const short8*>(bp + ks * 32);
        f32x4 acc[4] = {zero4, zero4, zero4, zero4};
        #pragma unroll
        for (int ks = 0; ks < 8; ++ks)
            #pragma unroll
            for (int mf = 0; mf < 4; ++mf)
                acc[mf] = __builtin_amdgcn_mfma_f32_16x16x32_bf16(aF[mf][ks], bF[ks], acc[mf], 0, 0, 0);
        #pragma unroll
        for (int mf = 0; mf < 4; ++mf)
            #pragma unroll
            for (int r = 0; r < 4; ++r) runL[mf][r] = fmaxf(runL[mf][r], acc[mf][r]);
    }
    #pragma unroll
    for (int mf = 0; mf < 4; ++mf)
        #pragma unroll
        for (int r = 0; r < 4; ++r) {
            float v = runL[mf][r];
            v = fmaxf(v, __shfl_xor(v, 1, 64));
            v = fmaxf(v, __shfl_xor(v, 2, 64));
            v = fmaxf(v, __shfl_xor(v, 4, 64));
            v = fmaxf(v, __shfl_xor(v, 8, 64));
            runL[mf][r] = v;
            if (l15 == 0) atomicMax(&smax[mf * 16 + lg * 4 + r], mapU(v));
        }
    __syncthreads();
    #pragma unroll
    for (int mf = 0; mf < 4; ++mf)
        #pragma unroll
        for (int r = 0; r < 4; ++r) runS[mf][r] = unmapU(smax[mf * 16 + lg * 4 + r]);

    // ---- main pass: all n, register-rotation pipelined ----
    short8 bF[8];
    #pragma unroll
    for (int ks = 0; ks < 8; ++ks) bF[ks] = *reinterpret_cast<const short8*>(basep + ks * 32);

    for (int c = 0; c < 63; ++c) {
        const int nrow = c * 128 + rowoff;
        const unsigned short* np = basep + (size_t)(c + 1) * 128 * 256;
        f32x4 acc[4] = {zero4, zero4, zero4, zero4};
        #pragma unroll
        for (int ks = 0; ks < 8; ++ks) {
            #pragma unroll
            for (int mf = 0; mf < 4; ++mf)
                acc[mf] = __builtin_amdgcn_mfma_f32_16x16x32_bf16(aF[mf][ks], bF[ks], acc[mf], 0, 0, 0);
            bF[ks] = *reinterpret_cast<const short8*>(np + ks * 32);   // rotate: reload after last use
        }

        unsigned qual = 0u;
        #pragma unroll
        for (int mf = 0; mf < 4; ++mf)
            #pragma unroll
            for (int r = 0; r < 4; ++r) {
                float dd = acc[mf][r];
                if (dd >= fmaxf(runS[mf][r], runL[mf][r]) - SCREEN_T) qual |= (1u << (mf * 4 + r));
                runL[mf][r] = fmaxf(runL[mf][r], dd);
            }
        if (qual) {
            #pragma unroll
            for (int mf = 0; mf < 4; ++mf)
                #pragma unroll
                for (int r = 0; r < 4; ++r)
                    if (qual & (1u << (mf * 4 + r))) {
                        int pix = mf * 16 + lg * 4 + r;
                        int s = atomicAdd(&scnt[pix], 1);
                        if (s < CAND_SLOTS) sbuf[pix][s] = nrow;
                    }
        }
        if ((c & 7) == 7) {
            #pragma unroll
            for (int mf = 0; mf < 4; ++mf)
                #pragma unroll
                for (int r = 0; r < 4; ++r) {
                    float v = runL[mf][r];
                    v = fmaxf(v, __shfl_xor(v, 1, 64));
                    v = fmaxf(v, __shfl_xor(v, 2, 64));
                    v = fmaxf(v, __shfl_xor(v, 4, 64));
                    v = fmaxf(v, __shfl_xor(v, 8, 64));
                    runL[mf][r] = v;
                    if (l15 == 0) atomicMax(&smax[mf * 16 + lg * 4 + r], mapU(v));
                }
            #pragma unroll
            for (int mf = 0; mf < 4; ++mf)
                #pragma unroll
                for (int r = 0; r < 4; ++r) runS[mf][r] = unmapU(smax[mf * 16 + lg * 4 + r]);
        }
    }
    {   // peeled final iteration c = 63 (no reload)
        const int c = 63;
        const int nrow = c * 128 + rowoff;
        f32x4 acc[4] = {zero4, zero4, zero4, zero4};
        #pragma unroll
        for (int ks = 0; ks < 8; ++ks)
            #pragma unroll
            for (int mf = 0; mf < 4; ++mf)
                acc[mf] = __builtin_amdgcn_mfma_f32_16x16x32_bf16(aF[mf][ks], bF[ks], acc[mf], 0, 0, 0);
        unsigned qual = 0u;
        #pragma unroll
        for (int mf = 0; mf < 4; ++mf)
            #pragma unroll
            for (int r = 0; r < 4; ++r) {
                float dd = acc[mf][r];
                if (dd >= fmaxf(runS[mf][r], runL[mf][r]) - SCREEN_T) qual |= (1u << (mf * 4 + r));
                runL[mf][r] = fmaxf(runL[mf][r], dd);
            }
        if (qual) {
            #pragma unroll
            for (int mf = 0; mf < 4; ++mf)
                #pragma unroll
                for (int r = 0; r < 4; ++r)
                    if (qual & (1u << (mf * 4 + r))) {
                        int pix = mf * 16 + lg * 4 + r;
                        int s = atomicAdd(&scnt[pix], 1);
                        if (s < CAND_SLOTS) sbuf[pix][s] = nrow;
                    }
        }
    }
    __syncthreads();
    if (tid < 64) ccnt[p0 + tid] = (scnt[tid] < CAND_SLOTS) ? scnt[tid] : CAND_SLOTS;
    for (int i = tid; i < 64 * CAND_SLOTS; i += 512) {
        int pix = i >> 7;                 // CAND_SLOTS == 128
        int s = i & (CAND_SLOTS - 1);
        if (s < scnt[pix] && s < CAND_SLOTS)
            cand[(size_t)(p0 + pix) * CAND_SLOTS + s] = sbuf[pix][s];
    }
}

// ---------------- exact rescore + fused per-pixel loss (bias applied on the fly) ------------
__global__ __launch_bounds__(256) void rescore_kernel(const float* __restrict__ ze,
                                                      const float* __restrict__ bias,
                                                      const float* __restrict__ mu_a,
                                                      const float* __restrict__ r_a,
                                                      const float* __restrict__ snorm,
                                                      const float* __restrict__ g,
                                                      const float* __restrict__ bta,
                                                      const float* __restrict__ cb,
                                                      const int* __restrict__ ccnt,
                                                      const int* __restrict__ cand,
                                                      int* __restrict__ idx_i,
                                                      float* __restrict__ idx_f,
                                                      float* __restrict__ losspp) {
    int p = blockIdx.x * 4 + (threadIdx.x >> 6);
    int lane = threadIdx.x & 63;
    int cnt = ccnt[p];
    if (cnt > CAND_SLOTS) cnt = CAND_SLOTS;
    float d = 3.4e38f;
    int ix = 0x7FFFFFFF;
    float mu = mu_a[p];
    float r = r_a[p];
    float sz = snorm[p];
    const float* zr = ze + (size_t)p * 256;
    for (int s = lane; s < cnt; s += 64) {
        int n = cand[(size_t)p * CAND_SLOTS + s];
        const float* cr = cb + (size_t)n * 256;
        float a0 = 0.f, a1 = 0.f, a2 = 0.f, a3 = 0.f;
        for (int k0 = 0; k0 < 256; k0 += 4) {
            float4 zq = *(const float4*)(zr + k0);
            float4 bb = *(const float4*)(bias + k0);
            float4 gq = *(const float4*)(g + k0);
            float4 bq = *(const float4*)(bta + k0);
            float4 cq = *(const float4*)(cr + k0);
            float x0 = zq.x + bb.x; float d0 = x0 - mu; float y0 = ((d0 * r) * gq.x) + bq.x;
            float x1 = zq.y + bb.y; float d1 = x1 - mu; float y1 = ((d1 * r) * gq.y) + bq.y;
            float x2 = zq.z + bb.z; float d2 = x2 - mu; float y2 = ((d2 * r) * gq.z) + bq.z;
            float x3 = zq.w + bb.w; float d3 = x3 - mu; float y3 = ((d3 * r) * gq.w) + bq.w;
            a0 = fmaf(y0, cq.x, a0);
            a1 = fmaf(y1, cq.y, a1);
            a2 = fmaf(y2, cq.z, a2);
            a3 = fmaf(y3, cq.w, a3);
        }
        float dot32 = (float)(((double)a0 + (double)a1) + ((double)a2 + (double)a3));
        float dd = fmaf(-2.0f, dot32, sz);
        if (dd < d || (dd == d && n < ix)) { d = dd; ix = n; }
    }
    #pragma unroll
    for (int off = 32; off > 0; off >>= 1) {
        float ov = __shfl_down(d, off, 64);
        int   oi = __shfl_down(ix, off, 64);
        if (ov < d || (ov == d && oi < ix)) { d = ov; ix = oi; }
    }
    if (lane == 0) {
        idx_i[p] = ix;
        idx_f[p] = (float)ix;
    }
    // ---- fused per-pixel loss: all 64 lanes, 4 elems each ----
    int ixw = __shfl(ix, 0, 64);
    const float* cr = cb + (size_t)ixw * 256;
    float4 cq = *(const float4*)(cr + lane * 4);
    float4 zq = *(const float4*)(zr + lane * 4);
    float4 bb = *(const float4*)(bias + lane * 4);
    float dx = cq.x - (zq.x + bb.x), dy = cq.y - (zq.y + bb.y);
    float dz = cq.z - (zq.z + bb.z), dw = cq.w - (zq.w + bb.w);
    float s = ((dx * dx + dy * dy) + (dz * dz + dw * dw));
    #pragma unroll
    for (int off = 32; off > 0; off >>= 1) s += __shfl_down(s, off, 64);
    if (lane == 0) losspp[p] = s;
}

// ---------------- final loss: single-block deterministic reduce over 16384 values ----------
__global__ void loss_final_kernel(const float* __restrict__ losspp, float* __restrict__ loss_out) {
    __shared__ float sbuf[4];
    float v = 0.f;
    for (int i = threadIdx.x; i < NPIX; i += 256) v += losspp[i];
    v = block_sum(v, sbuf);
    if (threadIdx.x == 0) *loss_out = v * (1.25f / (float)(NPIX * 256));
}

// ---------------- unemb conv as split-bf16 MFMA implicit GEMM ----------------
#define AROWB 128
#define ALO   13056
__global__ __launch_bounds__(256, 4) void conv_unemb_mfma(const unsigned short* __restrict__ cb_hi,
                                                          const unsigned short* __restrict__ cb_lo,
                                                          const int* __restrict__ idx,
                                                          const unsigned short* __restrict__ w2_hi,
                                                          const unsigned short* __restrict__ w2_lo,
                                                          const float* __restrict__ bias,
                                                          float* __restrict__ out) {
    __shared__ char smem[2 * ALO];
    float* ot = (float*)smem;
    const int tid = threadIdx.x;
    const int wid = tid >> 6, lane = tid & 63;
    const int l15 = lane & 15, lg = lane >> 4;
    const int bh = blockIdx.x;
    const int b = bh >> 5, h = bh & 31;
    const int ch = blockIdx.y;

    for (int i = tid; i < (2 * ALO) / 16; i += 256) ((int4*)smem)[i] = make_int4(0, 0, 0, 0);

    int nrow[3], rok[3], wpos[3], rr3[3];
    #pragma unroll
    for (int rd = 0; rd < 3; ++rd) {
        int t2 = rd * 256 + tid;
        int row = t2 >> 3;
        int r = row >> 5, w = row & 31;
        int hh = h + r - 1;
        rok[rd] = (hh >= 0 && hh < 32) ? 1 : 0;
        rr3[rd] = r; wpos[rd] = w;
        nrow[rd] = rok[rd] ? idx[(b * 32 + hh) * 32 + w] : 0;
    }
    __syncthreads();

    const f32x4 zero4 = {0.f, 0.f, 0.f, 0.f};
    f32x4 acc[2][2];
    acc[0][0] = zero4; acc[0][1] = zero4; acc[1][0] = zero4; acc[1][1] = zero4;

    for (int ec = 0; ec < 4; ++ec) {
        if (ec) __syncthreads();
        #pragma unroll
        for (int rd = 0; rd < 3; ++rd) {
            if (rok[rd]) {
                int t2 = rd * 256 + tid;
                int eo = (t2 & 7) * 8;
                size_t gsrc = (size_t)nrow[rd] * 256 + ec * 64 + eo;
                short8 vh = *(const short8*)(cb_hi + gsrc);
                short8 vl = *(const short8*)(cb_lo + gsrc);
                int wp = wpos[rd] + 1;
                int rowbase = (rr3[rd] * 34 + wp) * AROWB;
                int boff = (eo * 2) ^ ((wp & 7) << 4);
                *(short8*)(smem + rowbase + boff) = vh;
                *(short8*)(smem + ALO + rowbase + boff) = vl;
            }
        }
        __syncthreads();

        #pragma unroll
        for (int tap = 0; tap < 9; ++tap) {
            const int r = tap / 3, kw = tap % 3;
            #pragma unroll
            for (int ks = 0; ks < 2; ++ks) {
                int e2 = ks * 32 + lg * 8;
                short8 ah[2], al[2], bh2[2], bl2[2];
                #pragma unroll
                for (int mf = 0; mf < 2; ++mf) {
                    int wp = mf * 16 + l15 + kw;
                    int rowbase = (r * 34 + wp) * AROWB;
                    int boff = (e2 * 2) ^ ((wp & 7) << 4);
                    ah[mf] = *(const short8*)(smem + rowbase + boff);
                    al[mf] = *(const short8*)(smem + ALO + rowbase + boff);
                }
                #pragma unroll
                for (int nf = 0; nf < 2; ++nf) {
                    int cout = (ch << 7) + (wid << 5) + (nf << 4) + l15;
                    size_t goff = (size_t)cout * 2304 + tap * 256 + ec * 64 + e2;
                    bh2[nf] = *(const short8*)(w2_hi + goff);
                    bl2[nf] = *(const short8*)(w2_lo + goff);
                }
                #pragma unroll
                for (int mf = 0; mf < 2; ++mf)
                    #pragma unroll
                    for (int nf = 0; nf < 2; ++nf) {
                        acc[mf][nf] = __builtin_amdgcn_mfma_f32_16x16x32_bf16(ah[mf], bh2[nf], acc[mf][nf], 0, 0, 0);
                        acc[mf][nf] = __builtin_amdgcn_mfma_f32_16x16x32_bf16(ah[mf], bl2[nf], acc[mf][nf], 0, 0, 0);
                        acc[mf][nf] = __builtin_amdgcn_mfma_f32_16x16x32_bf16(al[mf], bh2[nf], acc[mf][nf], 0, 0, 0);
                    }
            }
        }
    }
    __syncthreads();
    #pragma unroll
    for (int mf = 0; mf < 2; ++mf)
        #pragma unroll
        for (int nf = 0; nf < 2; ++nf) {
            int cl = (wid << 5) + (nf << 4) + l15;
            #pragma unroll
            for (int rr = 0; rr < 4; ++rr) {
                int px = mf * 16 + lg * 4 + rr;
                ot[cl * 36 + px] = acc[mf][nf][rr];
            }
        }
    __syncthreads();
    int row = tid >> 1, half = tid & 1;
    int cout = (ch << 7) + row;
    float bv = bias[cout];
    float* dst = out + ((size_t)(b * 256 + cout) * 32 + h) * 32 + half * 16;
    const float* src = ot + row * 36 + half * 16;
    #pragma unroll
    for (int q = 0; q < 4; ++q) {
        float4 v = *(const float4*)(src + q * 4);
        v.x += bv; v.y += bv; v.z += bv; v.w += bv;
        *(float4*)(dst + q * 4) = v;
    }
}

extern "C" void kernel_launch(void* const* d_in, const int* in_sizes, int n_in,
                              void* d_out, int out_size, void* d_ws, size_t ws_size,
                              hipStream_t stream) {
    const float* z       = (const float*)d_in[0];
    const float* emb_w   = (const float*)d_in[1];
    const float* emb_b   = (const float*)d_in[2];
    const float* ln_g    = (const float*)d_in[3];
    const float* ln_b    = (const float*)d_in[4];
    const float* cb      = (const float*)d_in[5];
    const float* unemb_w = (const float*)d_in[6];
    const float* unemb_b = (const float*)d_in[7];

    float* out    = (float*)d_out;                    // [16,256,32,32]
    float* lossp  = out + OUT_ELEMS;                  // scalar
    float* idxf   = out + OUT_ELEMS + 1;              // [16384] as float

    // workspace layout (float slots)
    float* ws = (float*)d_ws;
    float* ze_t = ws;                                               // 4,194,304
    unsigned short* zf_bf = (unsigned short*)(ze_t + (size_t)NPIX * 256);      // 2,097,152 fl
    unsigned short* cb_hi = (unsigned short*)((float*)zf_bf + 2097152);        // 1,048,576 fl
    unsigned short* cb_lo = (unsigned short*)((float*)cb_hi + 1048576);        // 1,048,576 fl
    float* snorm = (float*)cb_lo + 1048576;                         // 16,384
    float* mu_a  = snorm + NPIX;                                    // 16,384
    float* r_a   = mu_a + NPIX;                                     // 16,384
    unsigned short* w1bh = (unsigned short*)(r_a + NPIX);           // 294,912 fl
    unsigned short* w1bl = (unsigned short*)((float*)w1bh + 294912);// 294,912 fl
    unsigned short* w2_hi = (unsigned short*)((float*)w1bl + 294912);   // 294,912 fl
    unsigned short* w2_lo = (unsigned short*)((float*)w2_hi + 294912);  // 294,912 fl
    int*   ccnt  = (int*)((float*)w2_lo + 294912);                  // 16,384
    int*   cand  = ccnt + NPIX;                                     // 2,097,152
    int*   idxi  = cand + (size_t)NPIX * CAND_SLOTS;                // 16,384
    float* losspp = (float*)(idxi + NPIX);                          // 16,384

    hipLaunchKernelGGL(prep_kernel, dim3(6656), dim3(256), 0, stream,
                       emb_w, w1bh, w1bl, unemb_w, w2_hi, w2_lo, cb, cb_hi, cb_lo);
    hipLaunchKernelGGL(conv_emb_mfma, dim3(512, 2), dim3(256), 0, stream, z, w1bh, w1bl, ze_t);
    hipLaunchKernelGGL(ln_kernel, dim3(NPIX / 4), dim3(256), 0, stream, ze_t, emb_b, ln_g, ln_b,
                       zf_bf, snorm, mu_a, r_a);
    hipLaunchKernelGGL(screen_kernel, dim3(256), dim3(512), 0, stream, zf_bf, cb_hi, ccnt, cand);
    hipLaunchKernelGGL(rescore_kernel, dim3(NPIX / 4), dim3(256), 0, stream,
                       ze_t, emb_b, mu_a, r_a, snorm, ln_g, ln_b, cb, ccnt, cand, idxi, idxf, losspp);
    hipLaunchKernelGGL(loss_final_kernel, dim3(1), dim3(256), 0, stream, losspp, lossp);
    hipLaunchKernelGGL(conv_unemb_mfma, dim3(512, 2), dim3(256), 0, stream,
                       cb_hi, cb_lo, idxi, w2_hi, w2_lo, unemb_b, out);
}

// Round 21
// 537.606 us; speedup vs baseline: 1.0103x; 1.0103x over previous
//
#include <hip/hip_runtime.h>
#include <hip/hip_bf16.h>

#define B_SZ 16
#define CIN 256
#define EDIM 256
#define NE 8192
#define HW 32
#define NPIX (B_SZ*HW*HW)          // 16384
#define OUT_ELEMS (B_SZ*CIN*HW*HW) // 4194304
#define SCREEN_T 3.2e-4f
#define CAND_SLOTS 128

typedef __attribute__((ext_vector_type(8))) short short8;
typedef __attribute__((ext_vector_type(4))) short short4v;
typedef __attribute__((ext_vector_type(4))) float f32x4;

// ---------------- helpers ----------------
__device__ __forceinline__ float block_sum(float v, float* sbuf) {
    #pragma unroll
    for (int off = 32; off > 0; off >>= 1) v += __shfl_down(v, off, 64);
    int wid = threadIdx.x >> 6;
    int lane = threadIdx.x & 63;
    if (lane == 0) sbuf[wid] = v;
    __syncthreads();
    if (threadIdx.x == 0) sbuf[0] = sbuf[0] + sbuf[1] + sbuf[2] + sbuf[3];
    __syncthreads();
    float r = sbuf[0];
    __syncthreads();
    return r;
}

__device__ __forceinline__ double wave_sum_d(double v) {
    #pragma unroll
    for (int off = 32; off > 0; off >>= 1) v += __shfl_down(v, off, 64);
    return __shfl(v, 0, 64);
}

__device__ __forceinline__ unsigned short bf16rne(float f) {
    unsigned int u = __float_as_uint(f);
    unsigned int r = (u + 0x7FFFu + ((u >> 16) & 1u)) >> 16;
    return (unsigned short)r;
}
__device__ __forceinline__ float bf2f(unsigned short h) {
    return __uint_as_float((unsigned int)h << 16);
}

// monotone map float -> uint (order-preserving), and inverse
__device__ __forceinline__ unsigned int mapU(float f) {
    unsigned int u = __float_as_uint(f);
    return (u & 0x80000000u) ? ~u : (u | 0x80000000u);
}
__device__ __forceinline__ float unmapU(unsigned int m) {
    unsigned int u = (m & 0x80000000u) ? (m ^ 0x80000000u) : ~m;
    return __uint_as_float(u);
}

// ---------------- fused prep: w1 bf16 hi/lo + w2 bf16 hi/lo + codebook bf16 hi/lo ----------
__global__ void prep_kernel(const float* __restrict__ emb_w, unsigned short* __restrict__ w1bh,
                            unsigned short* __restrict__ w1bl,
                            const float* __restrict__ unemb_w, unsigned short* __restrict__ w2hi,
                            unsigned short* __restrict__ w2lo, const float* __restrict__ cb,
                            unsigned short* __restrict__ cbhi, unsigned short* __restrict__ cblo) {
    int blk = blockIdx.x;
    if (blk < 2304) {
        int e = blk / 9, tap = blk % 9;
        int c = threadIdx.x;
        float v = emb_w[(size_t)e * 2304 + c * 9 + tap];
        unsigned short h = bf16rne(v);
        unsigned short l = bf16rne(v - bf2f(h));
        size_t j = (size_t)e * 2304 + tap * 256 + c;
        w1bh[j] = h; w1bl[j] = l;
    } else if (blk < 4608) {
        int b2 = blk - 2304;
        int cout = b2 / 9, tap = b2 % 9;
        int e = threadIdx.x;
        float v = unemb_w[(size_t)cout * 2304 + e * 9 + tap];
        unsigned short h = bf16rne(v);
        unsigned short l = bf16rne(v - bf2f(h));
        size_t j = (size_t)cout * 2304 + tap * 256 + e;
        w2hi[j] = h; w2lo[j] = l;
    } else {
        int i = (blk - 4608) * 256 + threadIdx.x;
        size_t base = (size_t)i * 4;
        float4 v = *(const float4*)(cb + base);
        short4v sh, sl;
        unsigned short h;
        h = bf16rne(v.x); sh[0] = (short)h; sl[0] = (short)bf16rne(v.x - bf2f(h));
        h = bf16rne(v.y); sh[1] = (short)h; sl[1] = (short)bf16rne(v.y - bf2f(h));
        h = bf16rne(v.z); sh[2] = (short)h; sl[2] = (short)bf16rne(v.z - bf2f(h));
        h = bf16rne(v.w); sh[3] = (short)h; sl[3] = (short)bf16rne(v.w - bf2f(h));
        *(short4v*)(cbhi + base) = sh;
        *(short4v*)(cblo + base) = sl;
    }
}

// ---------------- emb conv as split-bf16 MFMA implicit GEMM ----------------
// One 512-thread block per (b,h) row: 8 waves cover all 256 e; z staged/split ONCE
// (was twice with the (512,2) grid). Per-output arithmetic bit-identical.
#define EM_REG 6528   // bytes per split region: 102 rows x 64 B
__global__ __launch_bounds__(512) void conv_emb_mfma(const float* __restrict__ z,
                                                     const unsigned short* __restrict__ w1bh,
                                                     const unsigned short* __restrict__ w1bl,
                                                     float* __restrict__ ze) {
    __shared__ char smem[3 * EM_REG];   // 19584 B
    const int tid = threadIdx.x;
    const int wid = tid >> 6, lane = tid & 63;
    const int l15 = lane & 15, lg = lane >> 4;
    const int bh = blockIdx.x;
    const int b = bh >> 5, h = bh & 31;

    for (int i = tid; i < (3 * EM_REG) / 16; i += 512) ((int4*)smem)[i] = make_int4(0, 0, 0, 0);

    const f32x4 zero4 = {0.f, 0.f, 0.f, 0.f};
    f32x4 acc[2][2];
    acc[0][0] = zero4; acc[0][1] = zero4; acc[1][0] = zero4; acc[1][1] = zero4;

    for (int cc = 0; cc < 256; cc += 32) {
        __syncthreads();
        if (tid < 408) {
            int row = tid >> 2;              // 0..101 = r*34 + wp
            int oct = tid & 3;               // c-octet
            int r = row / 34, wp = row - r * 34;
            int hh = h + r - 1;
            if (hh >= 0 && hh < 32 && wp >= 1 && wp <= 32) {
                const float* zp = z + (size_t)b * 262144 + (size_t)(cc + oct * 8) * 1024
                                + hh * 32 + (wp - 1);
                short8 vh, vm, vl;
                #pragma unroll
                for (int j = 0; j < 8; ++j) {
                    float v = zp[(size_t)j * 1024];
                    unsigned short h1 = bf16rne(v);
                    float rm = v - bf2f(h1);
                    unsigned short m1 = bf16rne(rm);
                    float rl = rm - bf2f(m1);
                    unsigned short l1 = bf16rne(rl);
                    vh[j] = (short)h1; vm[j] = (short)m1; vl[j] = (short)l1;
                }
                int boff = row * 64 + ((oct * 16) ^ ((wp & 3) << 4));
                *(short8*)(smem + boff) = vh;
                *(short8*)(smem + EM_REG + boff) = vm;
                *(short8*)(smem + 2 * EM_REG + boff) = vl;
            }
        }
        __syncthreads();

        #pragma unroll
        for (int tap = 0; tap < 9; ++tap) {
            const int r = tap / 3, kw = tap % 3;
            short8 a1[2], a2[2], a3[2], bhf[2], blf[2];
            #pragma unroll
            for (int mf = 0; mf < 2; ++mf) {
                int wpr = mf * 16 + l15 + kw;   // 0..33
                int boff = (r * 34 + wpr) * 64 + ((lg * 16) ^ ((wpr & 3) << 4));
                a1[mf] = *(const short8*)(smem + boff);
                a2[mf] = *(const short8*)(smem + EM_REG + boff);
                a3[mf] = *(const short8*)(smem + 2 * EM_REG + boff);
            }
            #pragma unroll
            for (int nf = 0; nf < 2; ++nf) {
                int e_idx = (wid << 5) + (nf << 4) + l15;
                size_t goff = (size_t)e_idx * 2304 + tap * 256 + cc + lg * 8;
                bhf[nf] = *(const short8*)(w1bh + goff);
                blf[nf] = *(const short8*)(w1bl + goff);
            }
            #pragma unroll
            for (int mf = 0; mf < 2; ++mf)
                #pragma unroll
                for (int nf = 0; nf < 2; ++nf) {
                    acc[mf][nf] = __builtin_amdgcn_mfma_f32_16x16x32_bf16(a1[mf], bhf[nf], acc[mf][nf], 0, 0, 0);
                    acc[mf][nf] = __builtin_amdgcn_mfma_f32_16x16x32_bf16(a1[mf], blf[nf], acc[mf][nf], 0, 0, 0);
                    acc[mf][nf] = __builtin_amdgcn_mfma_f32_16x16x32_bf16(a2[mf], bhf[nf], acc[mf][nf], 0, 0, 0);
                    acc[mf][nf] = __builtin_amdgcn_mfma_f32_16x16x32_bf16(a2[mf], blf[nf], acc[mf][nf], 0, 0, 0);
                    acc[mf][nf] = __builtin_amdgcn_mfma_f32_16x16x32_bf16(a3[mf], bhf[nf], acc[mf][nf], 0, 0, 0);
                }
        }
    }

    int p0 = (b * 32 + h) * 32;
    #pragma unroll
    for (int mf = 0; mf < 2; ++mf)
        #pragma unroll
        for (int nf = 0; nf < 2; ++nf) {
            int e_idx = (wid << 5) + (nf << 4) + l15;
            #pragma unroll
            for (int rr = 0; rr < 4; ++rr) {
                int pix = mf * 16 + lg * 4 + rr;
                ze[(size_t)(p0 + pix) * 256 + e_idx] = acc[mf][nf][rr];
            }
        }
}

// ---------------- layernorm: wave-per-pixel, read-only ze (bias applied on the fly) --------
__global__ __launch_bounds__(256) void ln_kernel(const float* __restrict__ ze, const float* __restrict__ bias,
                                                 const float* __restrict__ g,
                                                 const float* __restrict__ bta,
                                                 unsigned short* __restrict__ zfb,
                                                 float* __restrict__ snorm, float* __restrict__ mu_a,
                                                 float* __restrict__ r_a) {
    int wid = threadIdx.x >> 6, lane = threadIdx.x & 63;
    int p = blockIdx.x * 4 + wid;
    const float* zp = ze + (size_t)p * 256;
    float x0 = zp[lane]       + bias[lane];
    float x1 = zp[lane + 64]  + bias[lane + 64];
    float x2 = zp[lane + 128] + bias[lane + 128];
    float x3 = zp[lane + 192] + bias[lane + 192];
    double lsum = (((double)x0 + (double)x1) + (double)x2) + (double)x3;
    double sum = wave_sum_d(lsum);
    float mu = ((float)sum) / 256.0f;
    float e0 = x0 - mu, e1 = x1 - mu, e2 = x2 - mu, e3 = x3 - mu;
    double lsq = (((double)(e0 * e0) + (double)(e1 * e1)) + (double)(e2 * e2)) + (double)(e3 * e3);
    double vs = wave_sum_d(lsq);
    float var = ((float)vs) / 256.0f;
    float r = 1.0f / sqrtf(var + 1e-5f);
    float y0 = ((e0 * r) * g[lane])       + bta[lane];
    float y1 = ((e1 * r) * g[lane + 64])  + bta[lane + 64];
    float y2 = ((e2 * r) * g[lane + 128]) + bta[lane + 128];
    float y3 = ((e3 * r) * g[lane + 192]) + bta[lane + 192];
    unsigned short* zq = zfb + (size_t)p * 256;
    zq[lane] = bf16rne(y0); zq[lane + 64] = bf16rne(y1);
    zq[lane + 128] = bf16rne(y2); zq[lane + 192] = bf16rne(y3);
    double lys = (((double)(y0 * y0) + (double)(y1 * y1)) + (double)(y2 * y2)) + (double)(y3 * y3);
    double ss = wave_sum_d(lys);
    if (lane == 0) { snorm[p] = (float)ss; mu_a[p] = mu; r_a[p] = r; }
}

// ---------------- single-pass screening: register-rotation pipelined B stream ----------------
__global__ __launch_bounds__(512) void screen_kernel(const unsigned short* __restrict__ zf_bf,
                                                     const unsigned short* __restrict__ cb_bf,
                                                     int* __restrict__ ccnt,
                                                     int* __restrict__ cand) {
    __shared__ unsigned int smax[64];
    __shared__ int scnt[64];
    __shared__ int sbuf[64][CAND_SLOTS];   // 32 KB
    const int tid = threadIdx.x;
    const int w = tid >> 6;
    const int lane = tid & 63;
    const int l15 = lane & 15, lg = lane >> 4;
    const int p0 = blockIdx.x * 64;
    const int rowoff = w * 16 + l15;
    const int lg8 = lg * 8;

    if (tid < 64) { smax[tid] = 0u; scnt[tid] = 0; }
    __syncthreads();

    short8 aF[4][8];
    #pragma unroll
    for (int mf = 0; mf < 4; ++mf)
        #pragma unroll
        for (int ks = 0; ks < 8; ++ks)
            aF[mf][ks] = *reinterpret_cast<const short8*>(
                zf_bf + (size_t)(p0 + mf * 16 + l15) * 256 + ks * 32 + lg8);

    const f32x4 zero4 = {0.f, 0.f, 0.f, 0.f};
    float runL[4][4], runS[4][4];
    #pragma unroll
    for (int mf = 0; mf < 4; ++mf)
        #pragma unroll
        for (int r = 0; r < 4; ++r) { runL[mf][r] = -3.4e38f; runS[mf][r] = -3.4e38f; }

    const unsigned short* basep = cb_bf + (size_t)rowoff * 256 + lg8;

    // ---- seed pass: n = 0..255 (2 chunks), max only ----
    for (int c = 0; c < 2; ++c) {
        const unsigned short* bp = basep + (size_t)c * 128 * 256;
        short8 bF[8];
        #pragma unroll
        for (int ks = 0; ks < 8; ++ks) bF[ks] = *reinterpret_cast<const short8*>(bp + ks * 32);
        f32x4 acc[4] = {zero4, zero4, zero4, zero4};
        #pragma unroll
        for (int ks = 0; ks < 8; ++ks)
            #pragma unroll
            for (int mf = 0; mf < 4; ++mf)
                acc[mf] = __builtin_amdgcn_mfma_f32_16x16x32_bf16(aF[mf][ks], bF[ks], acc[mf], 0, 0, 0);
        #pragma unroll
        for (int mf = 0; mf < 4; ++mf)
            #pragma unroll
            for (int r = 0; r < 4; ++r) runL[mf][r] = fmaxf(runL[mf][r], acc[mf][r]);
    }
    #pragma unroll
    for (int mf = 0; mf < 4; ++mf)
        #pragma unroll
        for (int r = 0; r < 4; ++r) {
            float v = runL[mf][r];
            v = fmaxf(v, __shfl_xor(v, 1, 64));
            v = fmaxf(v, __shfl_xor(v, 2, 64));
            v = fmaxf(v, __shfl_xor(v, 4, 64));
            v = fmaxf(v, __shfl_xor(v, 8, 64));
            runL[mf][r] = v;
            if (l15 == 0) atomicMax(&smax[mf * 16 + lg * 4 + r], mapU(v));
        }
    __syncthreads();
    #pragma unroll
    for (int mf = 0; mf < 4; ++mf)
        #pragma unroll
        for (int r = 0; r < 4; ++r) runS[mf][r] = unmapU(smax[mf * 16 + lg * 4 + r]);

    // ---- main pass: all n, register-rotation pipelined ----
    short8 bF[8];
    #pragma unroll
    for (int ks = 0; ks < 8; ++ks) bF[ks] = *reinterpret_cast<const short8*>(basep + ks * 32);

    for (int c = 0; c < 63; ++c) {
        const int nrow = c * 128 + rowoff;
        const unsigned short* np = basep + (size_t)(c + 1) * 128 * 256;
        f32x4 acc[4] = {zero4, zero4, zero4, zero4};
        #pragma unroll
        for (int ks = 0; ks < 8; ++ks) {
            #pragma unroll
            for (int mf = 0; mf < 4; ++mf)
                acc[mf] = __builtin_amdgcn_mfma_f32_16x16x32_bf16(aF[mf][ks], bF[ks], acc[mf], 0, 0, 0);
            bF[ks] = *reinterpret_cast<const short8*>(np + ks * 32);   // rotate: reload after last use
        }

        unsigned qual = 0u;
        #pragma unroll
        for (int mf = 0; mf < 4; ++mf)
            #pragma unroll
            for (int r = 0; r < 4; ++r) {
                float dd = acc[mf][r];
                if (dd >= fmaxf(runS[mf][r], runL[mf][r]) - SCREEN_T) qual |= (1u << (mf * 4 + r));
                runL[mf][r] = fmaxf(runL[mf][r], dd);
            }
        if (qual) {
            #pragma unroll
            for (int mf = 0; mf < 4; ++mf)
                #pragma unroll
                for (int r = 0; r < 4; ++r)
                    if (qual & (1u << (mf * 4 + r))) {
                        int pix = mf * 16 + lg * 4 + r;
                        int s = atomicAdd(&scnt[pix], 1);
                        if (s < CAND_SLOTS) sbuf[pix][s] = nrow;
                    }
        }
        if ((c & 7) == 7) {
            #pragma unroll
            for (int mf = 0; mf < 4; ++mf)
                #pragma unroll
                for (int r = 0; r < 4; ++r) {
                    float v = runL[mf][r];
                    v = fmaxf(v, __shfl_xor(v, 1, 64));
                    v = fmaxf(v, __shfl_xor(v, 2, 64));
                    v = fmaxf(v, __shfl_xor(v, 4, 64));
                    v = fmaxf(v, __shfl_xor(v, 8, 64));
                    runL[mf][r] = v;
                    if (l15 == 0) atomicMax(&smax[mf * 16 + lg * 4 + r], mapU(v));
                }
            #pragma unroll
            for (int mf = 0; mf < 4; ++mf)
                #pragma unroll
                for (int r = 0; r < 4; ++r) runS[mf][r] = unmapU(smax[mf * 16 + lg * 4 + r]);
        }
    }
    {   // peeled final iteration c = 63 (no reload)
        const int c = 63;
        const int nrow = c * 128 + rowoff;
        f32x4 acc[4] = {zero4, zero4, zero4, zero4};
        #pragma unroll
        for (int ks = 0; ks < 8; ++ks)
            #pragma unroll
            for (int mf = 0; mf < 4; ++mf)
                acc[mf] = __builtin_amdgcn_mfma_f32_16x16x32_bf16(aF[mf][ks], bF[ks], acc[mf], 0, 0, 0);
        unsigned qual = 0u;
        #pragma unroll
        for (int mf = 0; mf < 4; ++mf)
            #pragma unroll
            for (int r = 0; r < 4; ++r) {
                float dd = acc[mf][r];
                if (dd >= fmaxf(runS[mf][r], runL[mf][r]) - SCREEN_T) qual |= (1u << (mf * 4 + r));
                runL[mf][r] = fmaxf(runL[mf][r], dd);
            }
        if (qual) {
            #pragma unroll
            for (int mf = 0; mf < 4; ++mf)
                #pragma unroll
                for (int r = 0; r < 4; ++r)
                    if (qual & (1u << (mf * 4 + r))) {
                        int pix = mf * 16 + lg * 4 + r;
                        int s = atomicAdd(&scnt[pix], 1);
                        if (s < CAND_SLOTS) sbuf[pix][s] = nrow;
                    }
        }
    }
    __syncthreads();
    if (tid < 64) ccnt[p0 + tid] = (scnt[tid] < CAND_SLOTS) ? scnt[tid] : CAND_SLOTS;
    for (int i = tid; i < 64 * CAND_SLOTS; i += 512) {
        int pix = i >> 7;                 // CAND_SLOTS == 128
        int s = i & (CAND_SLOTS - 1);
        if (s < scnt[pix] && s < CAND_SLOTS)
            cand[(size_t)(p0 + pix) * CAND_SLOTS + s] = sbuf[pix][s];
    }
}

// ---------------- exact rescore + fused per-pixel loss (bias applied on the fly) ------------
__global__ __launch_bounds__(256) void rescore_kernel(const float* __restrict__ ze,
                                                      const float* __restrict__ bias,
                                                      const float* __restrict__ mu_a,
                                                      const float* __restrict__ r_a,
                                                      const float* __restrict__ snorm,
                                                      const float* __restrict__ g,
                                                      const float* __restrict__ bta,
                                                      const float* __restrict__ cb,
                                                      const int* __restrict__ ccnt,
                                                      const int* __restrict__ cand,
                                                      int* __restrict__ idx_i,
                                                      float* __restrict__ idx_f,
                                                      float* __restrict__ losspp) {
    int p = blockIdx.x * 4 + (threadIdx.x >> 6);
    int lane = threadIdx.x & 63;
    int cnt = ccnt[p];
    if (cnt > CAND_SLOTS) cnt = CAND_SLOTS;
    float d = 3.4e38f;
    int ix = 0x7FFFFFFF;
    float mu = mu_a[p];
    float r = r_a[p];
    float sz = snorm[p];
    const float* zr = ze + (size_t)p * 256;
    for (int s = lane; s < cnt; s += 64) {
        int n = cand[(size_t)p * CAND_SLOTS + s];
        const float* cr = cb + (size_t)n * 256;
        float a0 = 0.f, a1 = 0.f, a2 = 0.f, a3 = 0.f;
        for (int k0 = 0; k0 < 256; k0 += 4) {
            float4 zq = *(const float4*)(zr + k0);
            float4 bb = *(const float4*)(bias + k0);
            float4 gq = *(const float4*)(g + k0);
            float4 bq = *(const float4*)(bta + k0);
            float4 cq = *(const float4*)(cr + k0);
            float x0 = zq.x + bb.x; float d0 = x0 - mu; float y0 = ((d0 * r) * gq.x) + bq.x;
            float x1 = zq.y + bb.y; float d1 = x1 - mu; float y1 = ((d1 * r) * gq.y) + bq.y;
            float x2 = zq.z + bb.z; float d2 = x2 - mu; float y2 = ((d2 * r) * gq.z) + bq.z;
            float x3 = zq.w + bb.w; float d3 = x3 - mu; float y3 = ((d3 * r) * gq.w) + bq.w;
            a0 = fmaf(y0, cq.x, a0);
            a1 = fmaf(y1, cq.y, a1);
            a2 = fmaf(y2, cq.z, a2);
            a3 = fmaf(y3, cq.w, a3);
        }
        float dot32 = (float)(((double)a0 + (double)a1) + ((double)a2 + (double)a3));
        float dd = fmaf(-2.0f, dot32, sz);
        if (dd < d || (dd == d && n < ix)) { d = dd; ix = n; }
    }
    #pragma unroll
    for (int off = 32; off > 0; off >>= 1) {
        float ov = __shfl_down(d, off, 64);
        int   oi = __shfl_down(ix, off, 64);
        if (ov < d || (ov == d && oi < ix)) { d = ov; ix = oi; }
    }
    if (lane == 0) {
        idx_i[p] = ix;
        idx_f[p] = (float)ix;
    }
    // ---- fused per-pixel loss: all 64 lanes, 4 elems each ----
    int ixw = __shfl(ix, 0, 64);
    const float* cr = cb + (size_t)ixw * 256;
    float4 cq = *(const float4*)(cr + lane * 4);
    float4 zq = *(const float4*)(zr + lane * 4);
    float4 bb = *(const float4*)(bias + lane * 4);
    float dx = cq.x - (zq.x + bb.x), dy = cq.y - (zq.y + bb.y);
    float dz = cq.z - (zq.z + bb.z), dw = cq.w - (zq.w + bb.w);
    float s = ((dx * dx + dy * dy) + (dz * dz + dw * dw));
    #pragma unroll
    for (int off = 32; off > 0; off >>= 1) s += __shfl_down(s, off, 64);
    if (lane == 0) losspp[p] = s;
}

// ---------------- final loss: single-block deterministic reduce over 16384 values ----------
__global__ void loss_final_kernel(const float* __restrict__ losspp, float* __restrict__ loss_out) {
    __shared__ float sbuf[4];
    float v = 0.f;
    for (int i = threadIdx.x; i < NPIX; i += 256) v += losspp[i];
    v = block_sum(v, sbuf);
    if (threadIdx.x == 0) *loss_out = v * (1.25f / (float)(NPIX * 256));
}

// ---------------- unemb conv as split-bf16 MFMA implicit GEMM ----------------
#define AROWB 128
#define ALO   13056
__global__ __launch_bounds__(256, 4) void conv_unemb_mfma(const unsigned short* __restrict__ cb_hi,
                                                          const unsigned short* __restrict__ cb_lo,
                                                          const int* __restrict__ idx,
                                                          const unsigned short* __restrict__ w2_hi,
                                                          const unsigned short* __restrict__ w2_lo,
                                                          const float* __restrict__ bias,
                                                          float* __restrict__ out) {
    __shared__ char smem[2 * ALO];
    float* ot = (float*)smem;
    const int tid = threadIdx.x;
    const int wid = tid >> 6, lane = tid & 63;
    const int l15 = lane & 15, lg = lane >> 4;
    const int bh = blockIdx.x;
    const int b = bh >> 5, h = bh & 31;
    const int ch = blockIdx.y;

    for (int i = tid; i < (2 * ALO) / 16; i += 256) ((int4*)smem)[i] = make_int4(0, 0, 0, 0);

    int nrow[3], rok[3], wpos[3], rr3[3];
    #pragma unroll
    for (int rd = 0; rd < 3; ++rd) {
        int t2 = rd * 256 + tid;
        int row = t2 >> 3;
        int r = row >> 5, w = row & 31;
        int hh = h + r - 1;
        rok[rd] = (hh >= 0 && hh < 32) ? 1 : 0;
        rr3[rd] = r; wpos[rd] = w;
        nrow[rd] = rok[rd] ? idx[(b * 32 + hh) * 32 + w] : 0;
    }
    __syncthreads();

    const f32x4 zero4 = {0.f, 0.f, 0.f, 0.f};
    f32x4 acc[2][2];
    acc[0][0] = zero4; acc[0][1] = zero4; acc[1][0] = zero4; acc[1][1] = zero4;

    for (int ec = 0; ec < 4; ++ec) {
        if (ec) __syncthreads();
        #pragma unroll
        for (int rd = 0; rd < 3; ++rd) {
            if (rok[rd]) {
                int t2 = rd * 256 + tid;
                int eo = (t2 & 7) * 8;
                size_t gsrc = (size_t)nrow[rd] * 256 + ec * 64 + eo;
                short8 vh = *(const short8*)(cb_hi + gsrc);
                short8 vl = *(const short8*)(cb_lo + gsrc);
                int wp = wpos[rd] + 1;
                int rowbase = (rr3[rd] * 34 + wp) * AROWB;
                int boff = (eo * 2) ^ ((wp & 7) << 4);
                *(short8*)(smem + rowbase + boff) = vh;
                *(short8*)(smem + ALO + rowbase + boff) = vl;
            }
        }
        __syncthreads();

        #pragma unroll
        for (int tap = 0; tap < 9; ++tap) {
            const int r = tap / 3, kw = tap % 3;
            #pragma unroll
            for (int ks = 0; ks < 2; ++ks) {
                int e2 = ks * 32 + lg * 8;
                short8 ah[2], al[2], bh2[2], bl2[2];
                #pragma unroll
                for (int mf = 0; mf < 2; ++mf) {
                    int wp = mf * 16 + l15 + kw;
                    int rowbase = (r * 34 + wp) * AROWB;
                    int boff = (e2 * 2) ^ ((wp & 7) << 4);
                    ah[mf] = *(const short8*)(smem + rowbase + boff);
                    al[mf] = *(const short8*)(smem + ALO + rowbase + boff);
                }
                #pragma unroll
                for (int nf = 0; nf < 2; ++nf) {
                    int cout = (ch << 7) + (wid << 5) + (nf << 4) + l15;
                    size_t goff = (size_t)cout * 2304 + tap * 256 + ec * 64 + e2;
                    bh2[nf] = *(const short8*)(w2_hi + goff);
                    bl2[nf] = *(const short8*)(w2_lo + goff);
                }
                #pragma unroll
                for (int mf = 0; mf < 2; ++mf)
                    #pragma unroll
                    for (int nf = 0; nf < 2; ++nf) {
                        acc[mf][nf] = __builtin_amdgcn_mfma_f32_16x16x32_bf16(ah[mf], bh2[nf], acc[mf][nf], 0, 0, 0);
                        acc[mf][nf] = __builtin_amdgcn_mfma_f32_16x16x32_bf16(ah[mf], bl2[nf], acc[mf][nf], 0, 0, 0);
                        acc[mf][nf] = __builtin_amdgcn_mfma_f32_16x16x32_bf16(al[mf], bh2[nf], acc[mf][nf], 0, 0, 0);
                    }
            }
        }
    }
    __syncthreads();
    #pragma unroll
    for (int mf = 0; mf < 2; ++mf)
        #pragma unroll
        for (int nf = 0; nf < 2; ++nf) {
            int cl = (wid << 5) + (nf << 4) + l15;
            #pragma unroll
            for (int rr = 0; rr < 4; ++rr) {
                int px = mf * 16 + lg * 4 + rr;
                ot[cl * 36 + px] = acc[mf][nf][rr];
            }
        }
    __syncthreads();
    int row = tid >> 1, half = tid & 1;
    int cout = (ch << 7) + row;
    float bv = bias[cout];
    float* dst = out + ((size_t)(b * 256 + cout) * 32 + h) * 32 + half * 16;
    const float* src = ot + row * 36 + half * 16;
    #pragma unroll
    for (int q = 0; q < 4; ++q) {
        float4 v = *(const float4*)(src + q * 4);
        v.x += bv; v.y += bv; v.z += bv; v.w += bv;
        *(float4*)(dst + q * 4) = v;
    }
}

extern "C" void kernel_launch(void* const* d_in, const int* in_sizes, int n_in,
                              void* d_out, int out_size, void* d_ws, size_t ws_size,
                              hipStream_t stream) {
    const float* z       = (const float*)d_in[0];
    const float* emb_w   = (const float*)d_in[1];
    const float* emb_b   = (const float*)d_in[2];
    const float* ln_g    = (const float*)d_in[3];
    const float* ln_b    = (const float*)d_in[4];
    const float* cb      = (const float*)d_in[5];
    const float* unemb_w = (const float*)d_in[6];
    const float* unemb_b = (const float*)d_in[7];

    float* out    = (float*)d_out;                    // [16,256,32,32]
    float* lossp  = out + OUT_ELEMS;                  // scalar
    float* idxf   = out + OUT_ELEMS + 1;              // [16384] as float

    // workspace layout (float slots)
    float* ws = (float*)d_ws;
    float* ze_t = ws;                                               // 4,194,304
    unsigned short* zf_bf = (unsigned short*)(ze_t + (size_t)NPIX * 256);      // 2,097,152 fl
    unsigned short* cb_hi = (unsigned short*)((float*)zf_bf + 2097152);        // 1,048,576 fl
    unsigned short* cb_lo = (unsigned short*)((float*)cb_hi + 1048576);        // 1,048,576 fl
    float* snorm = (float*)cb_lo + 1048576;                         // 16,384
    float* mu_a  = snorm + NPIX;                                    // 16,384
    float* r_a   = mu_a + NPIX;                                     // 16,384
    unsigned short* w1bh = (unsigned short*)(r_a + NPIX);           // 294,912 fl
    unsigned short* w1bl = (unsigned short*)((float*)w1bh + 294912);// 294,912 fl
    unsigned short* w2_hi = (unsigned short*)((float*)w1bl + 294912);   // 294,912 fl
    unsigned short* w2_lo = (unsigned short*)((float*)w2_hi + 294912);  // 294,912 fl
    int*   ccnt  = (int*)((float*)w2_lo + 294912);                  // 16,384
    int*   cand  = ccnt + NPIX;                                     // 2,097,152
    int*   idxi  = cand + (size_t)NPIX * CAND_SLOTS;                // 16,384
    float* losspp = (float*)(idxi + NPIX);                          // 16,384

    hipLaunchKernelGGL(prep_kernel, dim3(6656), dim3(256), 0, stream,
                       emb_w, w1bh, w1bl, unemb_w, w2_hi, w2_lo, cb, cb_hi, cb_lo);
    hipLaunchKernelGGL(conv_emb_mfma, dim3(512), dim3(512), 0, stream, z, w1bh, w1bl, ze_t);
    hipLaunchKernelGGL(ln_kernel, dim3(NPIX / 4), dim3(256), 0, stream, ze_t, emb_b, ln_g, ln_b,
                       zf_bf, snorm, mu_a, r_a);
    hipLaunchKernelGGL(screen_kernel, dim3(256), dim3(512), 0, stream, zf_bf, cb_hi, ccnt, cand);
    hipLaunchKernelGGL(rescore_kernel, dim3(NPIX / 4), dim3(256), 0, stream,
                       ze_t, emb_b, mu_a, r_a, snorm, ln_g, ln_b, cb, ccnt, cand, idxi, idxf, losspp);
    hipLaunchKernelGGL(loss_final_kernel, dim3(1), dim3(256), 0, stream, losspp, lossp);
    hipLaunchKernelGGL(conv_unemb_mfma, dim3(512, 2), dim3(256), 0, stream,
                       cb_hi, cb_lo, idxi, w2_hi, w2_lo, unemb_b, out);
}

// Round 22
// 537.030 us; speedup vs baseline: 1.0114x; 1.0011x over previous
//
#include <hip/hip_runtime.h>
#include <hip/hip_bf16.h>

#define B_SZ 16
#define CIN 256
#define EDIM 256
#define NE 8192
#define HW 32
#define NPIX (B_SZ*HW*HW)          // 16384
#define OUT_ELEMS (B_SZ*CIN*HW*HW) // 4194304
#define SCREEN_T 3.2e-4f
#define CAND_SLOTS 128

typedef __attribute__((ext_vector_type(8))) short short8;
typedef __attribute__((ext_vector_type(4))) short short4v;
typedef __attribute__((ext_vector_type(4))) float f32x4;

// ---------------- helpers ----------------
__device__ __forceinline__ float block_sum(float v, float* sbuf) {
    #pragma unroll
    for (int off = 32; off > 0; off >>= 1) v += __shfl_down(v, off, 64);
    int wid = threadIdx.x >> 6;
    int lane = threadIdx.x & 63;
    if (lane == 0) sbuf[wid] = v;
    __syncthreads();
    if (threadIdx.x == 0) sbuf[0] = sbuf[0] + sbuf[1] + sbuf[2] + sbuf[3];
    __syncthreads();
    float r = sbuf[0];
    __syncthreads();
    return r;
}

__device__ __forceinline__ double wave_sum_d(double v) {
    #pragma unroll
    for (int off = 32; off > 0; off >>= 1) v += __shfl_down(v, off, 64);
    return __shfl(v, 0, 64);
}

__device__ __forceinline__ unsigned short bf16rne(float f) {
    unsigned int u = __float_as_uint(f);
    unsigned int r = (u + 0x7FFFu + ((u >> 16) & 1u)) >> 16;
    return (unsigned short)r;
}
__device__ __forceinline__ float bf2f(unsigned short h) {
    return __uint_as_float((unsigned int)h << 16);
}

// monotone map float -> uint (order-preserving), and inverse
__device__ __forceinline__ unsigned int mapU(float f) {
    unsigned int u = __float_as_uint(f);
    return (u & 0x80000000u) ? ~u : (u | 0x80000000u);
}
__device__ __forceinline__ float unmapU(unsigned int m) {
    unsigned int u = (m & 0x80000000u) ? (m ^ 0x80000000u) : ~m;
    return __uint_as_float(u);
}

// ---------------- fused prep: w1 bf16 hi/lo + w2 bf16 hi/lo + codebook bf16 hi/lo ----------
__global__ void prep_kernel(const float* __restrict__ emb_w, unsigned short* __restrict__ w1bh,
                            unsigned short* __restrict__ w1bl,
                            const float* __restrict__ unemb_w, unsigned short* __restrict__ w2hi,
                            unsigned short* __restrict__ w2lo, const float* __restrict__ cb,
                            unsigned short* __restrict__ cbhi, unsigned short* __restrict__ cblo) {
    int blk = blockIdx.x;
    if (blk < 2304) {
        int e = blk / 9, tap = blk % 9;
        int c = threadIdx.x;
        float v = emb_w[(size_t)e * 2304 + c * 9 + tap];
        unsigned short h = bf16rne(v);
        unsigned short l = bf16rne(v - bf2f(h));
        size_t j = (size_t)e * 2304 + tap * 256 + c;
        w1bh[j] = h; w1bl[j] = l;
    } else if (blk < 4608) {
        int b2 = blk - 2304;
        int cout = b2 / 9, tap = b2 % 9;
        int e = threadIdx.x;
        float v = unemb_w[(size_t)cout * 2304 + e * 9 + tap];
        unsigned short h = bf16rne(v);
        unsigned short l = bf16rne(v - bf2f(h));
        size_t j = (size_t)cout * 2304 + tap * 256 + e;
        w2hi[j] = h; w2lo[j] = l;
    } else {
        int i = (blk - 4608) * 256 + threadIdx.x;
        size_t base = (size_t)i * 4;
        float4 v = *(const float4*)(cb + base);
        short4v sh, sl;
        unsigned short h;
        h = bf16rne(v.x); sh[0] = (short)h; sl[0] = (short)bf16rne(v.x - bf2f(h));
        h = bf16rne(v.y); sh[1] = (short)h; sl[1] = (short)bf16rne(v.y - bf2f(h));
        h = bf16rne(v.z); sh[2] = (short)h; sl[2] = (short)bf16rne(v.z - bf2f(h));
        h = bf16rne(v.w); sh[3] = (short)h; sl[3] = (short)bf16rne(v.w - bf2f(h));
        *(short4v*)(cbhi + base) = sh;
        *(short4v*)(cblo + base) = sl;
    }
}

// ---------------- emb conv as split-bf16 MFMA implicit GEMM, double-buffered staging -------
// One 512-thread block per (b,h) row. Two LDS buffers: stage chunk c+1 while computing
// chunk c; ONE barrier per chunk (was two). Chunk/tap/accumulate order unchanged ->
// bit-identical ze. Pad entries zeroed once per buffer, never overwritten.
#define EM_REG 6528            // bytes per split region: 102 rows x 64 B
#define EM_BUF (3 * EM_REG)    // 19584 B per buffer
__global__ __launch_bounds__(512) void conv_emb_mfma(const float* __restrict__ z,
                                                     const unsigned short* __restrict__ w1bh,
                                                     const unsigned short* __restrict__ w1bl,
                                                     float* __restrict__ ze) {
    __shared__ char smem[2 * EM_BUF];   // 39168 B
    const int tid = threadIdx.x;
    const int wid = tid >> 6, lane = tid & 63;
    const int l15 = lane & 15, lg = lane >> 4;
    const int bh = blockIdx.x;
    const int b = bh >> 5, h = bh & 31;

    // staging role (invariant across chunks)
    const int srow = tid >> 2;              // 0..101 = r*34 + wp (for tid < 408)
    const int soct = tid & 3;
    const int sr = srow / 34, swp = srow - sr * 34;
    const int shh = h + sr - 1;
    const bool sok = (tid < 408) && (shh >= 0) && (shh < 32) && (swp >= 1) && (swp <= 32);
    const int sboff = srow * 64 + ((soct * 16) ^ ((swp & 3) << 4));

    // zero both buffers (pads stay zero forever)
    for (int i = tid; i < (2 * EM_BUF) / 16; i += 512) ((int4*)smem)[i] = make_int4(0, 0, 0, 0);
    __syncthreads();

    // stage chunk 0 into buffer 0
    if (sok) {
        const float* zp = z + (size_t)b * 262144 + (size_t)(soct * 8) * 1024 + shh * 32 + (swp - 1);
        short8 vh, vm, vl;
        #pragma unroll
        for (int j = 0; j < 8; ++j) {
            float v = zp[(size_t)j * 1024];
            unsigned short h1 = bf16rne(v);
            float rm = v - bf2f(h1);
            unsigned short m1 = bf16rne(rm);
            float rl = rm - bf2f(m1);
            unsigned short l1 = bf16rne(rl);
            vh[j] = (short)h1; vm[j] = (short)m1; vl[j] = (short)l1;
        }
        *(short8*)(smem + sboff) = vh;
        *(short8*)(smem + EM_REG + sboff) = vm;
        *(short8*)(smem + 2 * EM_REG + sboff) = vl;
    }
    __syncthreads();

    const f32x4 zero4 = {0.f, 0.f, 0.f, 0.f};
    f32x4 acc[2][2];
    acc[0][0] = zero4; acc[0][1] = zero4; acc[1][0] = zero4; acc[1][1] = zero4;

    for (int ci = 0; ci < 8; ++ci) {
        const int cc = ci * 32;
        char* cur = smem + (ci & 1) * EM_BUF;
        char* nxt = smem + ((ci & 1) ^ 1) * EM_BUF;

        // stage next chunk into nxt (loads overlap the MFMAs below)
        if (ci < 7 && sok) {
            const float* zp = z + (size_t)b * 262144 + (size_t)(cc + 32 + soct * 8) * 1024
                            + shh * 32 + (swp - 1);
            short8 vh, vm, vl;
            #pragma unroll
            for (int j = 0; j < 8; ++j) {
                float v = zp[(size_t)j * 1024];
                unsigned short h1 = bf16rne(v);
                float rm = v - bf2f(h1);
                unsigned short m1 = bf16rne(rm);
                float rl = rm - bf2f(m1);
                unsigned short l1 = bf16rne(rl);
                vh[j] = (short)h1; vm[j] = (short)m1; vl[j] = (short)l1;
            }
            *(short8*)(nxt + sboff) = vh;
            *(short8*)(nxt + EM_REG + sboff) = vm;
            *(short8*)(nxt + 2 * EM_REG + sboff) = vl;
        }

        // compute chunk ci from cur
        #pragma unroll
        for (int tap = 0; tap < 9; ++tap) {
            const int r = tap / 3, kw = tap % 3;
            short8 a1[2], a2[2], a3[2], bhf[2], blf[2];
            #pragma unroll
            for (int mf = 0; mf < 2; ++mf) {
                int wpr = mf * 16 + l15 + kw;   // 0..33
                int boff = (r * 34 + wpr) * 64 + ((lg * 16) ^ ((wpr & 3) << 4));
                a1[mf] = *(const short8*)(cur + boff);
                a2[mf] = *(const short8*)(cur + EM_REG + boff);
                a3[mf] = *(const short8*)(cur + 2 * EM_REG + boff);
            }
            #pragma unroll
            for (int nf = 0; nf < 2; ++nf) {
                int e_idx = (wid << 5) + (nf << 4) + l15;
                size_t goff = (size_t)e_idx * 2304 + tap * 256 + cc + lg * 8;
                bhf[nf] = *(const short8*)(w1bh + goff);
                blf[nf] = *(const short8*)(w1bl + goff);
            }
            #pragma unroll
            for (int mf = 0; mf < 2; ++mf)
                #pragma unroll
                for (int nf = 0; nf < 2; ++nf) {
                    acc[mf][nf] = __builtin_amdgcn_mfma_f32_16x16x32_bf16(a1[mf], bhf[nf], acc[mf][nf], 0, 0, 0);
                    acc[mf][nf] = __builtin_amdgcn_mfma_f32_16x16x32_bf16(a1[mf], blf[nf], acc[mf][nf], 0, 0, 0);
                    acc[mf][nf] = __builtin_amdgcn_mfma_f32_16x16x32_bf16(a2[mf], bhf[nf], acc[mf][nf], 0, 0, 0);
                    acc[mf][nf] = __builtin_amdgcn_mfma_f32_16x16x32_bf16(a2[mf], blf[nf], acc[mf][nf], 0, 0, 0);
                    acc[mf][nf] = __builtin_amdgcn_mfma_f32_16x16x32_bf16(a3[mf], bhf[nf], acc[mf][nf], 0, 0, 0);
                }
        }
        __syncthreads();
    }

    int p0 = (b * 32 + h) * 32;
    #pragma unroll
    for (int mf = 0; mf < 2; ++mf)
        #pragma unroll
        for (int nf = 0; nf < 2; ++nf) {
            int e_idx = (wid << 5) + (nf << 4) + l15;
            #pragma unroll
            for (int rr = 0; rr < 4; ++rr) {
                int pix = mf * 16 + lg * 4 + rr;
                ze[(size_t)(p0 + pix) * 256 + e_idx] = acc[mf][nf][rr];
            }
        }
}

// ---------------- layernorm: wave-per-pixel, read-only ze (bias applied on the fly) --------
__global__ __launch_bounds__(256) void ln_kernel(const float* __restrict__ ze, const float* __restrict__ bias,
                                                 const float* __restrict__ g,
                                                 const float* __restrict__ bta,
                                                 unsigned short* __restrict__ zfb,
                                                 float* __restrict__ snorm, float* __restrict__ mu_a,
                                                 float* __restrict__ r_a) {
    int wid = threadIdx.x >> 6, lane = threadIdx.x & 63;
    int p = blockIdx.x * 4 + wid;
    const float* zp = ze + (size_t)p * 256;
    float x0 = zp[lane]       + bias[lane];
    float x1 = zp[lane + 64]  + bias[lane + 64];
    float x2 = zp[lane + 128] + bias[lane + 128];
    float x3 = zp[lane + 192] + bias[lane + 192];
    double lsum = (((double)x0 + (double)x1) + (double)x2) + (double)x3;
    double sum = wave_sum_d(lsum);
    float mu = ((float)sum) / 256.0f;
    float e0 = x0 - mu, e1 = x1 - mu, e2 = x2 - mu, e3 = x3 - mu;
    double lsq = (((double)(e0 * e0) + (double)(e1 * e1)) + (double)(e2 * e2)) + (double)(e3 * e3);
    double vs = wave_sum_d(lsq);
    float var = ((float)vs) / 256.0f;
    float r = 1.0f / sqrtf(var + 1e-5f);
    float y0 = ((e0 * r) * g[lane])       + bta[lane];
    float y1 = ((e1 * r) * g[lane + 64])  + bta[lane + 64];
    float y2 = ((e2 * r) * g[lane + 128]) + bta[lane + 128];
    float y3 = ((e3 * r) * g[lane + 192]) + bta[lane + 192];
    unsigned short* zq = zfb + (size_t)p * 256;
    zq[lane] = bf16rne(y0); zq[lane + 64] = bf16rne(y1);
    zq[lane + 128] = bf16rne(y2); zq[lane + 192] = bf16rne(y3);
    double lys = (((double)(y0 * y0) + (double)(y1 * y1)) + (double)(y2 * y2)) + (double)(y3 * y3);
    double ss = wave_sum_d(lys);
    if (lane == 0) { snorm[p] = (float)ss; mu_a[p] = mu; r_a[p] = r; }
}

// ---------------- single-pass screening: register-rotation pipelined B stream ----------------
__global__ __launch_bounds__(512) void screen_kernel(const unsigned short* __restrict__ zf_bf,
                                                     const unsigned short* __restrict__ cb_bf,
                                                     int* __restrict__ ccnt,
                                                     int* __restrict__ cand) {
    __shared__ unsigned int smax[64];
    __shared__ int scnt[64];
    __shared__ int sbuf[64][CAND_SLOTS];   // 32 KB
    const int tid = threadIdx.x;
    const int w = tid >> 6;
    const int lane = tid & 63;
    const int l15 = lane & 15, lg = lane >> 4;
    const int p0 = blockIdx.x * 64;
    const int rowoff = w * 16 + l15;
    const int lg8 = lg * 8;

    if (tid < 64) { smax[tid] = 0u; scnt[tid] = 0; }
    __syncthreads();

    short8 aF[4][8];
    #pragma unroll
    for (int mf = 0; mf < 4; ++mf)
        #pragma unroll
        for (int ks = 0; ks < 8; ++ks)
            aF[mf][ks] = *reinterpret_cast<const short8*>(
                zf_bf + (size_t)(p0 + mf * 16 + l15) * 256 + ks * 32 + lg8);

    const f32x4 zero4 = {0.f, 0.f, 0.f, 0.f};
    float runL[4][4], runS[4][4];
    #pragma unroll
    for (int mf = 0; mf < 4; ++mf)
        #pragma unroll
        for (int r = 0; r < 4; ++r) { runL[mf][r] = -3.4e38f; runS[mf][r] = -3.4e38f; }

    const unsigned short* basep = cb_bf + (size_t)rowoff * 256 + lg8;

    // ---- seed pass: n = 0..255 (2 chunks), max only ----
    for (int c = 0; c < 2; ++c) {
        const unsigned short* bp = basep + (size_t)c * 128 * 256;
        short8 bF[8];
        #pragma unroll
        for (int ks = 0; ks < 8; ++ks) bF[ks] = *reinterpret_cast<const short8*>(bp + ks * 32);
        f32x4 acc[4] = {zero4, zero4, zero4, zero4};
        #pragma unroll
        for (int ks = 0; ks < 8; ++ks)
            #pragma unroll
            for (int mf = 0; mf < 4; ++mf)
                acc[mf] = __builtin_amdgcn_mfma_f32_16x16x32_bf16(aF[mf][ks], bF[ks], acc[mf], 0, 0, 0);
        #pragma unroll
        for (int mf = 0; mf < 4; ++mf)
            #pragma unroll
            for (int r = 0; r < 4; ++r) runL[mf][r] = fmaxf(runL[mf][r], acc[mf][r]);
    }
    #pragma unroll
    for (int mf = 0; mf < 4; ++mf)
        #pragma unroll
        for (int r = 0; r < 4; ++r) {
            float v = runL[mf][r];
            v = fmaxf(v, __shfl_xor(v, 1, 64));
            v = fmaxf(v, __shfl_xor(v, 2, 64));
            v = fmaxf(v, __shfl_xor(v, 4, 64));
            v = fmaxf(v, __shfl_xor(v, 8, 64));
            runL[mf][r] = v;
            if (l15 == 0) atomicMax(&smax[mf * 16 + lg * 4 + r], mapU(v));
        }
    __syncthreads();
    #pragma unroll
    for (int mf = 0; mf < 4; ++mf)
        #pragma unroll
        for (int r = 0; r < 4; ++r) runS[mf][r] = unmapU(smax[mf * 16 + lg * 4 + r]);

    // ---- main pass: all n, register-rotation pipelined ----
    short8 bF[8];
    #pragma unroll
    for (int ks = 0; ks < 8; ++ks) bF[ks] = *reinterpret_cast<const short8*>(basep + ks * 32);

    for (int c = 0; c < 63; ++c) {
        const int nrow = c * 128 + rowoff;
        const unsigned short* np = basep + (size_t)(c + 1) * 128 * 256;
        f32x4 acc[4] = {zero4, zero4, zero4, zero4};
        #pragma unroll
        for (int ks = 0; ks < 8; ++ks) {
            #pragma unroll
            for (int mf = 0; mf < 4; ++mf)
                acc[mf] = __builtin_amdgcn_mfma_f32_16x16x32_bf16(aF[mf][ks], bF[ks], acc[mf], 0, 0, 0);
            bF[ks] = *reinterpret_cast<const short8*>(np + ks * 32);   // rotate: reload after last use
        }

        unsigned qual = 0u;
        #pragma unroll
        for (int mf = 0; mf < 4; ++mf)
            #pragma unroll
            for (int r = 0; r < 4; ++r) {
                float dd = acc[mf][r];
                if (dd >= fmaxf(runS[mf][r], runL[mf][r]) - SCREEN_T) qual |= (1u << (mf * 4 + r));
                runL[mf][r] = fmaxf(runL[mf][r], dd);
            }
        if (qual) {
            #pragma unroll
            for (int mf = 0; mf < 4; ++mf)
                #pragma unroll
                for (int r = 0; r < 4; ++r)
                    if (qual & (1u << (mf * 4 + r))) {
                        int pix = mf * 16 + lg * 4 + r;
                        int s = atomicAdd(&scnt[pix], 1);
                        if (s < CAND_SLOTS) sbuf[pix][s] = nrow;
                    }
        }
        if ((c & 7) == 7) {
            #pragma unroll
            for (int mf = 0; mf < 4; ++mf)
                #pragma unroll
                for (int r = 0; r < 4; ++r) {
                    float v = runL[mf][r];
                    v = fmaxf(v, __shfl_xor(v, 1, 64));
                    v = fmaxf(v, __shfl_xor(v, 2, 64));
                    v = fmaxf(v, __shfl_xor(v, 4, 64));
                    v = fmaxf(v, __shfl_xor(v, 8, 64));
                    runL[mf][r] = v;
                    if (l15 == 0) atomicMax(&smax[mf * 16 + lg * 4 + r], mapU(v));
                }
            #pragma unroll
            for (int mf = 0; mf < 4; ++mf)
                #pragma unroll
                for (int r = 0; r < 4; ++r) runS[mf][r] = unmapU(smax[mf * 16 + lg * 4 + r]);
        }
    }
    {   // peeled final iteration c = 63 (no reload)
        const int c = 63;
        const int nrow = c * 128 + rowoff;
        f32x4 acc[4] = {zero4, zero4, zero4, zero4};
        #pragma unroll
        for (int ks = 0; ks < 8; ++ks)
            #pragma unroll
            for (int mf = 0; mf < 4; ++mf)
                acc[mf] = __builtin_amdgcn_mfma_f32_16x16x32_bf16(aF[mf][ks], bF[ks], acc[mf], 0, 0, 0);
        unsigned qual = 0u;
        #pragma unroll
        for (int mf = 0; mf < 4; ++mf)
            #pragma unroll
            for (int r = 0; r < 4; ++r) {
                float dd = acc[mf][r];
                if (dd >= fmaxf(runS[mf][r], runL[mf][r]) - SCREEN_T) qual |= (1u << (mf * 4 + r));
                runL[mf][r] = fmaxf(runL[mf][r], dd);
            }
        if (qual) {
            #pragma unroll
            for (int mf = 0; mf < 4; ++mf)
                #pragma unroll
                for (int r = 0; r < 4; ++r)
                    if (qual & (1u << (mf * 4 + r))) {
                        int pix = mf * 16 + lg * 4 + r;
                        int s = atomicAdd(&scnt[pix], 1);
                        if (s < CAND_SLOTS) sbuf[pix][s] = nrow;
                    }
        }
    }
    __syncthreads();
    if (tid < 64) ccnt[p0 + tid] = (scnt[tid] < CAND_SLOTS) ? scnt[tid] : CAND_SLOTS;
    for (int i = tid; i < 64 * CAND_SLOTS; i += 512) {
        int pix = i >> 7;                 // CAND_SLOTS == 128
        int s = i & (CAND_SLOTS - 1);
        if (s < scnt[pix] && s < CAND_SLOTS)
            cand[(size_t)(p0 + pix) * CAND_SLOTS + s] = sbuf[pix][s];
    }
}

// ---------------- exact rescore + fused per-pixel loss (bias applied on the fly) ------------
__global__ __launch_bounds__(256) void rescore_kernel(const float* __restrict__ ze,
                                                      const float* __restrict__ bias,
                                                      const float* __restrict__ mu_a,
                                                      const float* __restrict__ r_a,
                                                      const float* __restrict__ snorm,
                                                      const float* __restrict__ g,
                                                      const float* __restrict__ bta,
                                                      const float* __restrict__ cb,
                                                      const int* __restrict__ ccnt,
                                                      const int* __restrict__ cand,
                                                      int* __restrict__ idx_i,
                                                      float* __restrict__ idx_f,
                                                      float* __restrict__ losspp) {
    int p = blockIdx.x * 4 + (threadIdx.x >> 6);
    int lane = threadIdx.x & 63;
    int cnt = ccnt[p];
    if (cnt > CAND_SLOTS) cnt = CAND_SLOTS;
    float d = 3.4e38f;
    int ix = 0x7FFFFFFF;
    float mu = mu_a[p];
    float r = r_a[p];
    float sz = snorm[p];
    const float* zr = ze + (size_t)p * 256;
    for (int s = lane; s < cnt; s += 64) {
        int n = cand[(size_t)p * CAND_SLOTS + s];
        const float* cr = cb + (size_t)n * 256;
        float a0 = 0.f, a1 = 0.f, a2 = 0.f, a3 = 0.f;
        for (int k0 = 0; k0 < 256; k0 += 4) {
            float4 zq = *(const float4*)(zr + k0);
            float4 bb = *(const float4*)(bias + k0);
            float4 gq = *(const float4*)(g + k0);
            float4 bq = *(const float4*)(bta + k0);
            float4 cq = *(const float4*)(cr + k0);
            float x0 = zq.x + bb.x; float d0 = x0 - mu; float y0 = ((d0 * r) * gq.x) + bq.x;
            float x1 = zq.y + bb.y; float d1 = x1 - mu; float y1 = ((d1 * r) * gq.y) + bq.y;
            float x2 = zq.z + bb.z; float d2 = x2 - mu; float y2 = ((d2 * r) * gq.z) + bq.z;
            float x3 = zq.w + bb.w; float d3 = x3 - mu; float y3 = ((d3 * r) * gq.w) + bq.w;
            a0 = fmaf(y0, cq.x, a0);
            a1 = fmaf(y1, cq.y, a1);
            a2 = fmaf(y2, cq.z, a2);
            a3 = fmaf(y3, cq.w, a3);
        }
        float dot32 = (float)(((double)a0 + (double)a1) + ((double)a2 + (double)a3));
        float dd = fmaf(-2.0f, dot32, sz);
        if (dd < d || (dd == d && n < ix)) { d = dd; ix = n; }
    }
    #pragma unroll
    for (int off = 32; off > 0; off >>= 1) {
        float ov = __shfl_down(d, off, 64);
        int   oi = __shfl_down(ix, off, 64);
        if (ov < d || (ov == d && oi < ix)) { d = ov; ix = oi; }
    }
    if (lane == 0) {
        idx_i[p] = ix;
        idx_f[p] = (float)ix;
    }
    // ---- fused per-pixel loss: all 64 lanes, 4 elems each ----
    int ixw = __shfl(ix, 0, 64);
    const float* cr = cb + (size_t)ixw * 256;
    float4 cq = *(const float4*)(cr + lane * 4);
    float4 zq = *(const float4*)(zr + lane * 4);
    float4 bb = *(const float4*)(bias + lane * 4);
    float dx = cq.x - (zq.x + bb.x), dy = cq.y - (zq.y + bb.y);
    float dz = cq.z - (zq.z + bb.z), dw = cq.w - (zq.w + bb.w);
    float s = ((dx * dx + dy * dy) + (dz * dz + dw * dw));
    #pragma unroll
    for (int off = 32; off > 0; off >>= 1) s += __shfl_down(s, off, 64);
    if (lane == 0) losspp[p] = s;
}

// ---------------- final loss: single-block deterministic reduce over 16384 values ----------
__global__ void loss_final_kernel(const float* __restrict__ losspp, float* __restrict__ loss_out) {
    __shared__ float sbuf[4];
    float v = 0.f;
    for (int i = threadIdx.x; i < NPIX; i += 256) v += losspp[i];
    v = block_sum(v, sbuf);
    if (threadIdx.x == 0) *loss_out = v * (1.25f / (float)(NPIX * 256));
}

// ---------------- unemb conv as split-bf16 MFMA implicit GEMM ----------------
#define AROWB 128
#define ALO   13056
__global__ __launch_bounds__(256, 4) void conv_unemb_mfma(const unsigned short* __restrict__ cb_hi,
                                                          const unsigned short* __restrict__ cb_lo,
                                                          const int* __restrict__ idx,
                                                          const unsigned short* __restrict__ w2_hi,
                                                          const unsigned short* __restrict__ w2_lo,
                                                          const float* __restrict__ bias,
                                                          float* __restrict__ out) {
    __shared__ char smem[2 * ALO];
    float* ot = (float*)smem;
    const int tid = threadIdx.x;
    const int wid = tid >> 6, lane = tid & 63;
    const int l15 = lane & 15, lg = lane >> 4;
    const int bh = blockIdx.x;
    const int b = bh >> 5, h = bh & 31;
    const int ch = blockIdx.y;

    for (int i = tid; i < (2 * ALO) / 16; i += 256) ((int4*)smem)[i] = make_int4(0, 0, 0, 0);

    int nrow[3], rok[3], wpos[3], rr3[3];
    #pragma unroll
    for (int rd = 0; rd < 3; ++rd) {
        int t2 = rd * 256 + tid;
        int row = t2 >> 3;
        int r = row >> 5, w = row & 31;
        int hh = h + r - 1;
        rok[rd] = (hh >= 0 && hh < 32) ? 1 : 0;
        rr3[rd] = r; wpos[rd] = w;
        nrow[rd] = rok[rd] ? idx[(b * 32 + hh) * 32 + w] : 0;
    }
    __syncthreads();

    const f32x4 zero4 = {0.f, 0.f, 0.f, 0.f};
    f32x4 acc[2][2];
    acc[0][0] = zero4; acc[0][1] = zero4; acc[1][0] = zero4; acc[1][1] = zero4;

    for (int ec = 0; ec < 4; ++ec) {
        if (ec) __syncthreads();
        #pragma unroll
        for (int rd = 0; rd < 3; ++rd) {
            if (rok[rd]) {
                int t2 = rd * 256 + tid;
                int eo = (t2 & 7) * 8;
                size_t gsrc = (size_t)nrow[rd] * 256 + ec * 64 + eo;
                short8 vh = *(const short8*)(cb_hi + gsrc);
                short8 vl = *(const short8*)(cb_lo + gsrc);
                int wp = wpos[rd] + 1;
                int rowbase = (rr3[rd] * 34 + wp) * AROWB;
                int boff = (eo * 2) ^ ((wp & 7) << 4);
                *(short8*)(smem + rowbase + boff) = vh;
                *(short8*)(smem + ALO + rowbase + boff) = vl;
            }
        }
        __syncthreads();

        #pragma unroll
        for (int tap = 0; tap < 9; ++tap) {
            const int r = tap / 3, kw = tap % 3;
            #pragma unroll
            for (int ks = 0; ks < 2; ++ks) {
                int e2 = ks * 32 + lg * 8;
                short8 ah[2], al[2], bh2[2], bl2[2];
                #pragma unroll
                for (int mf = 0; mf < 2; ++mf) {
                    int wp = mf * 16 + l15 + kw;
                    int rowbase = (r * 34 + wp) * AROWB;
                    int boff = (e2 * 2) ^ ((wp & 7) << 4);
                    ah[mf] = *(const short8*)(smem + rowbase + boff);
                    al[mf] = *(const short8*)(smem + ALO + rowbase + boff);
                }
                #pragma unroll
                for (int nf = 0; nf < 2; ++nf) {
                    int cout = (ch << 7) + (wid << 5) + (nf << 4) + l15;
                    size_t goff = (size_t)cout * 2304 + tap * 256 + ec * 64 + e2;
                    bh2[nf] = *(const short8*)(w2_hi + goff);
                    bl2[nf] = *(const short8*)(w2_lo + goff);
                }
                #pragma unroll
                for (int mf = 0; mf < 2; ++mf)
                    #pragma unroll
                    for (int nf = 0; nf < 2; ++nf) {
                        acc[mf][nf] = __builtin_amdgcn_mfma_f32_16x16x32_bf16(ah[mf], bh2[nf], acc[mf][nf], 0, 0, 0);
                        acc[mf][nf] = __builtin_amdgcn_mfma_f32_16x16x32_bf16(ah[mf], bl2[nf], acc[mf][nf], 0, 0, 0);
                        acc[mf][nf] = __builtin_amdgcn_mfma_f32_16x16x32_bf16(al[mf], bh2[nf], acc[mf][nf], 0, 0, 0);
                    }
            }
        }
    }
    __syncthreads();
    #pragma unroll
    for (int mf = 0; mf < 2; ++mf)
        #pragma unroll
        for (int nf = 0; nf < 2; ++nf) {
            int cl = (wid << 5) + (nf << 4) + l15;
            #pragma unroll
            for (int rr = 0; rr < 4; ++rr) {
                int px = mf * 16 + lg * 4 + rr;
                ot[cl * 36 + px] = acc[mf][nf][rr];
            }
        }
    __syncthreads();
    int row = tid >> 1, half = tid & 1;
    int cout = (ch << 7) + row;
    float bv = bias[cout];
    float* dst = out + ((size_t)(b * 256 + cout) * 32 + h) * 32 + half * 16;
    const float* src = ot + row * 36 + half * 16;
    #pragma unroll
    for (int q = 0; q < 4; ++q) {
        float4 v = *(const float4*)(src + q * 4);
        v.x += bv; v.y += bv; v.z += bv; v.w += bv;
        *(float4*)(dst + q * 4) = v;
    }
}

extern "C" void kernel_launch(void* const* d_in, const int* in_sizes, int n_in,
                              void* d_out, int out_size, void* d_ws, size_t ws_size,
                              hipStream_t stream) {
    const float* z       = (const float*)d_in[0];
    const float* emb_w   = (const float*)d_in[1];
    const float* emb_b   = (const float*)d_in[2];
    const float* ln_g    = (const float*)d_in[3];
    const float* ln_b    = (const float*)d_in[4];
    const float* cb      = (const float*)d_in[5];
    const float* unemb_w = (const float*)d_in[6];
    const float* unemb_b = (const float*)d_in[7];

    float* out    = (float*)d_out;                    // [16,256,32,32]
    float* lossp  = out + OUT_ELEMS;                  // scalar
    float* idxf   = out + OUT_ELEMS + 1;              // [16384] as float

    // workspace layout (float slots)
    float* ws = (float*)d_ws;
    float* ze_t = ws;                                               // 4,194,304
    unsigned short* zf_bf = (unsigned short*)(ze_t + (size_t)NPIX * 256);      // 2,097,152 fl
    unsigned short* cb_hi = (unsigned short*)((float*)zf_bf + 2097152);        // 1,048,576 fl
    unsigned short* cb_lo = (unsigned short*)((float*)cb_hi + 1048576);        // 1,048,576 fl
    float* snorm = (float*)cb_lo + 1048576;                         // 16,384
    float* mu_a  = snorm + NPIX;                                    // 16,384
    float* r_a   = mu_a + NPIX;                                     // 16,384
    unsigned short* w1bh = (unsigned short*)(r_a + NPIX);           // 294,912 fl
    unsigned short* w1bl = (unsigned short*)((float*)w1bh + 294912);// 294,912 fl
    unsigned short* w2_hi = (unsigned short*)((float*)w1bl + 294912);   // 294,912 fl
    unsigned short* w2_lo = (unsigned short*)((float*)w2_hi + 294912);  // 294,912 fl
    int*   ccnt  = (int*)((float*)w2_lo + 294912);                  // 16,384
    int*   cand  = ccnt + NPIX;                                     // 2,097,152
    int*   idxi  = cand + (size_t)NPIX * CAND_SLOTS;                // 16,384
    float* losspp = (float*)(idxi + NPIX);                          // 16,384

    hipLaunchKernelGGL(prep_kernel, dim3(6656), dim3(256), 0, stream,
                       emb_w, w1bh, w1bl, unemb_w, w2_hi, w2_lo, cb, cb_hi, cb_lo);
    hipLaunchKernelGGL(conv_emb_mfma, dim3(512), dim3(512), 0, stream, z, w1bh, w1bl, ze_t);
    hipLaunchKernelGGL(ln_kernel, dim3(NPIX / 4), dim3(256), 0, stream, ze_t, emb_b, ln_g, ln_b,
                       zf_bf, snorm, mu_a, r_a);
    hipLaunchKernelGGL(screen_kernel, dim3(256), dim3(512), 0, stream, zf_bf, cb_hi, ccnt, cand);
    hipLaunchKernelGGL(rescore_kernel, dim3(NPIX / 4), dim3(256), 0, stream,
                       ze_t, emb_b, mu_a, r_a, snorm, ln_g, ln_b, cb, ccnt, cand, idxi, idxf, losspp);
    hipLaunchKernelGGL(loss_final_kernel, dim3(1), dim3(256), 0, stream, losspp, lossp);
    hipLaunchKernelGGL(conv_unemb_mfma, dim3(512, 2), dim3(256), 0, stream,
                       cb_hi, cb_lo, idxi, w2_hi, w2_lo, unemb_b, out);
}